// Round 4
// baseline (418.983 us; speedup 1.0000x reference)
//
#include <hip/hip_runtime.h>
#include <cstdint>
#include <cstddef>

// x = x556 + x570 (fp32 [12544,1024]); LayerNorm over C=1024; y = xn @ W^T + b
// (W [4096,1024] fp32, row-major = B^T GEMM layout); out = gelu(y), fp32.
// Internal compute: bf16 MFMA 32x32x16; tanh-form GELU (|err| vs erf ~1e-3 << 6.4e-2 thr).
#define M_DIM 12544
#define K_DIM 1024
#define N_DIM 4096

typedef __bf16 bf16x8 __attribute__((ext_vector_type(8)));
typedef float f32x16 __attribute__((ext_vector_type(16)));

// Counted vmcnt (T4): loads stay in flight across raw s_barriers.
// Closing-barrier discipline (proven round 3): lgkmcnt(0) -> sched_barrier(0)
// -> s_barrier before any slot reuse; raw s_barrier alone does NOT drain lgkm.
#define VMCNT(n)   asm volatile("s_waitcnt vmcnt(" #n ")" ::: "memory")
#define LGKMCNT0() asm volatile("s_waitcnt lgkmcnt(0)" ::: "memory")
#define FENCE()    asm volatile("" ::: "memory")
#define SCHED0()   __builtin_amdgcn_sched_barrier(0)
#define BAR()      __builtin_amdgcn_s_barrier()

__device__ __forceinline__ unsigned short bf16_rne(float f) {
    unsigned int u = __float_as_uint(f);
    u += 0x7FFFu + ((u >> 16) & 1u);
    return (unsigned short)(u >> 16);
}
__device__ __forceinline__ unsigned int pack2_bf16(float lo, float hi) {
    return (unsigned int)bf16_rne(lo) | ((unsigned int)bf16_rne(hi) << 16);
}
// tanh-form GELU: x * sigmoid(1.5957691*x*(1+0.044715 x^2)); ~8 VALU ops vs erff's ~25.
__device__ __forceinline__ float gelu_fast(float x) {
    float t = 1.5957691216057308f * x * fmaf(0.044715f, x * x, 1.0f);
    float e = __expf(-t);                       // v_exp_f32
    return x * __builtin_amdgcn_rcpf(1.0f + e); // v_rcp_f32
}

// async global->LDS, 16B per lane. LDS dest must be wave-uniform base + lane*16.
__device__ __forceinline__ void async_load16(const void* g, void* l) {
    __builtin_amdgcn_global_load_lds(
        (const __attribute__((address_space(1))) void*)g,
        (__attribute__((address_space(3))) void*)l,
        16, 0, 0);
}

// -------- fused: residual add + LayerNorm -> bf16 xn  AND  W fp32 -> bf16 ----
// blocks [0,3136): LN rows (4 rows/block). blocks [3136,4160): W convert.
__global__ __launch_bounds__(256) void pre_fused(
    const float* __restrict__ x0,
    const float* __restrict__ x1,
    const float* __restrict__ gam,
    const float* __restrict__ bet,
    const float* __restrict__ Wlin,
    unsigned short* __restrict__ o,
    unsigned short* __restrict__ wb)
{
    const int bid = blockIdx.x;
    if (bid >= M_DIM / 4) {
        // W conversion: 1024 blocks x 256 threads x 16 elems = 4096*1024
        const int wbid = bid - M_DIM / 4;
        const float* wp = Wlin + (size_t)wbid * 4096;
        unsigned short* op = wb + (size_t)wbid * 4096;
        #pragma unroll
        for (int j = 0; j < 4; ++j) {
            float4 v = *(const float4*)(wp + j * 1024 + threadIdx.x * 4);
            uint2 r;
            r.x = pack2_bf16(v.x, v.y);
            r.y = pack2_bf16(v.z, v.w);
            *(uint2*)(op + j * 1024 + threadIdx.x * 4) = r;
        }
        return;
    }

    const int lane = threadIdx.x & 63;
    const int wv   = threadIdx.x >> 6;
    const size_t row = (size_t)bid * 4 + wv;
    const float* p0 = x0 + row * K_DIM;
    const float* p1 = x1 + row * K_DIM;

    float v[16];
    #pragma unroll
    for (int i = 0; i < 4; ++i) {
        float4 a = *(const float4*)(p0 + i * 256 + lane * 4);
        float4 b = *(const float4*)(p1 + i * 256 + lane * 4);
        v[4*i+0] = a.x + b.x; v[4*i+1] = a.y + b.y;
        v[4*i+2] = a.z + b.z; v[4*i+3] = a.w + b.w;
    }

    float s = 0.f, sq = 0.f;
    #pragma unroll
    for (int i = 0; i < 16; ++i) { s += v[i]; sq += v[i] * v[i]; }
    #pragma unroll
    for (int m = 32; m >= 1; m >>= 1) {
        s  += __shfl_xor(s,  m);
        sq += __shfl_xor(sq, m);
    }
    const float mean = s * (1.0f / 1024.0f);
    float var = sq * (1.0f / 1024.0f) - mean * mean;
    var = fmaxf(var, 0.0f);
    const float rstd = rsqrtf(var + 1e-5f);

    unsigned short* po = o + row * K_DIM;
    #pragma unroll
    for (int i = 0; i < 4; ++i) {
        float4 g  = *(const float4*)(gam + i * 256 + lane * 4);
        float4 be = *(const float4*)(bet + i * 256 + lane * 4);
        float y0 = (v[4*i+0] - mean) * rstd * g.x + be.x;
        float y1 = (v[4*i+1] - mean) * rstd * g.y + be.y;
        float y2 = (v[4*i+2] - mean) * rstd * g.z + be.z;
        float y3 = (v[4*i+3] - mean) * rstd * g.w + be.w;
        uint2 r;
        r.x = pack2_bf16(y0, y1);
        r.y = pack2_bf16(y2, y3);
        *(uint2*)(po + i * 256 + lane * 4) = r;
    }
}

// ---------------- GEMM: C[M,N] = gelu(A[M,K] @ B[N,K]^T + bias) ----------------
// 256x256 tile, BK=64, 512 threads = 8 waves (2Mx4N), per-wave 128x64 output
// via 4x2 of mfma_f32_32x32x16_bf16 (acc 4x2 f32x16 = 128 VGPR).
// LDS: 2-buf x (A 256x64 + B 256x64) bf16 = 128 KB -> 1 block/CU, 2 waves/SIMD.
//
// Staging: per K-tile, 4 rounds each for A,B; round r: thread t writes LDS
// bytes [r*8192 + t*16) = row (r*64 + t>>3), phys seg (t&7). Period-8 seg
// swizzle: phys = (lseg + row&7) & 7, applied on the GLOBAL source so the
// global_load_lds dest stays linear. Row stride (128 B) == one full bank row,
// so bank-quad == phys seg; a 16-lane fragment-read group (rows r..r+15, fixed
// lseg) covers all 8 segs exactly 2x -> conflict-free (2-way is free, m136).
//
// Pipeline (per K-tile t, buf c=t&1): stage(t+1 -> buf c^1, sealed by step
// t-1's closing barrier); VMCNT(8) drains exactly tile t's 8 loads (tile t+1's
// 8 stay in flight across the barrier, T4); BAR; compute in 4 k-step
// sub-phases, setprio(1) around each 8-MFMA cluster (T5: 2 waves/SIMD sit in
// different sub-phases); LGKMCNT0; BAR (seals buf c for reuse at step t+1).
__global__ __launch_bounds__(512, 2) void gemm_bias_gelu(
    const unsigned short* __restrict__ A,    // xn [M,K] bf16
    const unsigned short* __restrict__ B,    // W  [N,K] bf16
    const float* __restrict__ bias,          // [N] fp32
    float* __restrict__ C)                   // [M,N] fp32
{
    __shared__ __align__(16) unsigned short At[2][256 * 64];
    __shared__ __align__(16) unsigned short Bt[2][256 * 64];

    const int t  = threadIdx.x;          // 0..511
    const int bn = blockIdx.x;           // 0..15
    const int bm = blockIdx.y;           // 0..48
    const int m0 = bm * 256, n0 = bn * 256;

    // staging geometry: round r, thread t -> LDS elems r*4096 + t*8
    // (row r*64 + (t>>3), phys seg t&7); global lseg = (pseg - (row&7)) & 7.
    const int srow = t >> 3;             // 0..63 within a round
    const int lseg = ((t & 7) - (srow & 7)) & 7;
    const unsigned short* ag0 = A + (size_t)(m0 + srow      ) * K_DIM + lseg * 8;
    const unsigned short* ag1 = A + (size_t)(m0 + srow +  64) * K_DIM + lseg * 8;
    const unsigned short* ag2 = A + (size_t)(m0 + srow + 128) * K_DIM + lseg * 8;
    const unsigned short* ag3 = A + (size_t)(m0 + srow + 192) * K_DIM + lseg * 8;
    const unsigned short* bg0 = B + (size_t)(n0 + srow      ) * K_DIM + lseg * 8;
    const unsigned short* bg1 = B + (size_t)(n0 + srow +  64) * K_DIM + lseg * 8;
    const unsigned short* bg2 = B + (size_t)(n0 + srow + 128) * K_DIM + lseg * 8;
    const unsigned short* bg3 = B + (size_t)(n0 + srow + 192) * K_DIM + lseg * 8;

    const int lane = t & 63;
    const int wid  = t >> 6;             // 0..7
    const int wr   = wid >> 2;           // 0..1: rows wr*128..+128
    const int wc   = wid & 3;            // 0..3: cols wc*64..+64
    const int ml   = lane & 31;
    const int h    = lane >> 5;

    f32x16 acc[4][2] = {};

    // issue 8 async loads (one K-tile: 4 rounds A + 4 rounds B) into buf s
    auto stage = [&](int s) {
        async_load16(ag0, &At[s][        t * 8]);
        async_load16(ag1, &At[s][ 4096 + t * 8]);
        async_load16(ag2, &At[s][ 8192 + t * 8]);
        async_load16(ag3, &At[s][12288 + t * 8]);
        async_load16(bg0, &Bt[s][        t * 8]);
        async_load16(bg1, &Bt[s][ 4096 + t * 8]);
        async_load16(bg2, &Bt[s][ 8192 + t * 8]);
        async_load16(bg3, &Bt[s][12288 + t * 8]);
        ag0 += 64; ag1 += 64; ag2 += 64; ag3 += 64;
        bg0 += 64; bg1 += 64; bg2 += 64; bg3 += 64;
        FENCE();
    };

    // fragments: operand [dim=ml][k = ks*16 + h*8 + j], logical seg = ks*2+h,
    // phys seg = (lseg + (row&7)) & 7
    auto compute = [&](int b) {
        #pragma unroll
        for (int ks = 0; ks < 4; ++ks) {
            bf16x8 af[4], bfr[2];
            #pragma unroll
            for (int i = 0; i < 4; ++i) {
                const int ra = wr * 128 + i * 32 + ml;
                af[i] = *(const bf16x8*)&At[b][ra * 64 + ((((ks * 2 + h) + (ra & 7)) & 7) * 8)];
            }
            #pragma unroll
            for (int j = 0; j < 2; ++j) {
                const int rb = wc * 64 + j * 32 + ml;
                bfr[j] = *(const bf16x8*)&Bt[b][rb * 64 + ((((ks * 2 + h) + (rb & 7)) & 7) * 8)];
            }
            __builtin_amdgcn_s_setprio(1);
            #pragma unroll
            for (int i = 0; i < 4; ++i)
                #pragma unroll
                for (int j = 0; j < 2; ++j)
                    acc[i][j] = __builtin_amdgcn_mfma_f32_32x32x16_bf16(
                        af[i], bfr[j], acc[i][j], 0, 0, 0);
            __builtin_amdgcn_s_setprio(0);
        }
    };

    // prologue: tile 0 -> buf 0 (8 loads in flight)
    stage(0);

    // 16 K-tiles, 2 per iteration; step t: stage(t+1), drain tile t, compute.
    #pragma unroll 1
    for (int it = 0; it < 7; ++it) {
        stage(1); VMCNT(8); BAR(); SCHED0(); compute(0); LGKMCNT0(); SCHED0(); BAR();
        stage(0); VMCNT(8); BAR(); SCHED0(); compute(1); LGKMCNT0(); SCHED0(); BAR();
    }
    stage(1); VMCNT(8); BAR(); SCHED0(); compute(0); LGKMCNT0(); SCHED0(); BAR();  // tile 14
    VMCNT(0); BAR(); SCHED0(); compute(1);                                         // tile 15

    // epilogue: C/D layout col=ml (n), row=(reg&3)+8*(reg>>2)+4*h (m)
    #pragma unroll
    for (int j = 0; j < 2; ++j) {
        const int n = n0 + wc * 64 + j * 32 + ml;
        const float bj = bias[n];
        #pragma unroll
        for (int i = 0; i < 4; ++i) {
            const int mbase = m0 + wr * 128 + i * 32 + 4 * h;
            #pragma unroll
            for (int reg = 0; reg < 16; ++reg) {
                const int m = mbase + (reg & 3) + 8 * (reg >> 2);
                C[(size_t)m * N_DIM + n] = gelu_fast(acc[i][j][reg] + bj);
            }
        }
    }
}

extern "C" void kernel_launch(void* const* d_in, const int* in_sizes, int n_in,
                              void* d_out, int out_size, void* d_ws, size_t ws_size,
                              hipStream_t stream) {
    const float* x556 = (const float*)d_in[0];
    const float* x570 = (const float*)d_in[1];
    const float* gam  = (const float*)d_in[2];
    const float* bet  = (const float*)d_in[3];
    const float* Wlin = (const float*)d_in[4];
    const float* blin = (const float*)d_in[5];
    float* out = (float*)d_out;

    unsigned short* xn = (unsigned short*)d_ws;            // 25.69 MB
    unsigned short* wb = xn + (size_t)M_DIM * K_DIM;       // 8.39 MB

    pre_fused<<<M_DIM / 4 + 1024, 256, 0, stream>>>(x556, x570, gam, bet, Wlin, xn, wb);
    gemm_bias_gelu<<<dim3(N_DIM / 256, M_DIM / 256), 512, 0, stream>>>(xn, wb, blin, out);
}